// Round 1
// baseline (604.226 us; speedup 1.0000x reference)
//
#include <hip/hip_runtime.h>
#include <hip/hip_bf16.h>

// EquivariantLayerNorm: MULS=[128,64,32], DIMS=[1,3,5], FEAT=480, fp32.
// One wave (64 lanes) per row; 4 rows per 256-thread block.
// Row = 120 float4 chunks; field boundaries align to chunks (32 / 80).
// Memory-bound: 768 MB total traffic -> ~122 us floor at 6.3 TB/s.

#define ELN_EPS 1e-5f
#define FEAT 480
#define NF4 120   // float4 per row

__global__ __launch_bounds__(256) void eln_kernel(
    const float* __restrict__ in,
    const float* __restrict__ w,
    const float* __restrict__ b,
    float* __restrict__ out,
    int n_rows)
{
    __shared__ float s_w[FEAT];   // per-feature expanded weight
    __shared__ float s_b[128];    // bias for field 1 only

    // Stage expanded weights: w[f] for f<128; w[128+(f-128)/3] for f<320; w[192+(f-320)/5] else.
    for (int f = (int)threadIdx.x; f < FEAT; f += 256) {
        float wv;
        if (f < 128)       wv = w[f];
        else if (f < 320)  wv = w[128 + (f - 128) / 3];
        else               wv = w[192 + (f - 320) / 5];
        s_w[f] = wv;
    }
    if (threadIdx.x < 128) s_b[threadIdx.x] = b[threadIdx.x];
    __syncthreads();

    const int wave = (int)threadIdx.x >> 6;
    const int lane = (int)threadIdx.x & 63;
    const int row  = (int)blockIdx.x * 4 + wave;
    if (row >= n_rows) return;   // wave-uniform branch

    const float4* in4  = (const float4*)(in  + (size_t)row * FEAT);
    float4*       out4 = (float4*)      (out + (size_t)row * FEAT);

    // Load: chunk0 = idx lane (0..63), chunk1 = idx lane+64 (64..119, lanes 0..55 only)
    const bool has2 = (lane < 56);
    float4 a = in4[lane];
    float4 c = make_float4(0.f, 0.f, 0.f, 0.f);
    if (has2) c = in4[lane + 64];

    // Partial sums.
    // chunk0: idx<32 -> field1 (sum+sq), idx 32..63 -> field2 (sq)
    // chunk1: idx 64..79 (lane<16) -> field2, idx 80..119 (lane 16..55) -> field3
    float sum1 = 0.f, sq1 = 0.f, sq2 = 0.f, sq3 = 0.f;
    {
        float da = a.x*a.x + a.y*a.y + a.z*a.z + a.w*a.w;
        if (lane < 32) { sum1 = a.x + a.y + a.z + a.w; sq1 = da; }
        else           { sq2 = da; }
        float dc = c.x*c.x + c.y*c.y + c.z*c.z + c.w*c.w;  // zero for lanes >=56
        if (lane < 16) sq2 += dc;
        else           sq3  = dc;
    }

    // Butterfly reduction across the full 64-lane wave.
    #pragma unroll
    for (int off = 32; off > 0; off >>= 1) {
        sum1 += __shfl_xor(sum1, off);
        sq1  += __shfl_xor(sq1,  off);
        sq2  += __shfl_xor(sq2,  off);
        sq3  += __shfl_xor(sq3,  off);
    }

    const float mean = sum1 * (1.f / 128.f);
    const float var  = sq1 * (1.f / 128.f) - mean * mean;
    const float inv1 = rsqrtf(var + ELN_EPS);
    const float inv2 = rsqrtf(sq2 * (1.f / 192.f) + ELN_EPS);
    const float inv3 = rsqrtf(sq3 * (1.f / 160.f) + ELN_EPS);

    // Write chunk0
    {
        const int f0 = lane * 4;
        float4 wv = ((const float4*)s_w)[lane];
        float4 o;
        if (lane < 32) {
            float4 bv = ((const float4*)s_b)[lane];
            o.x = (a.x - mean) * inv1 * wv.x + bv.x;
            o.y = (a.y - mean) * inv1 * wv.y + bv.y;
            o.z = (a.z - mean) * inv1 * wv.z + bv.z;
            o.w = (a.w - mean) * inv1 * wv.w + bv.w;
        } else {
            o.x = a.x * inv2 * wv.x;
            o.y = a.y * inv2 * wv.y;
            o.z = a.z * inv2 * wv.z;
            o.w = a.w * inv2 * wv.w;
        }
        (void)f0;
        out4[lane] = o;
    }
    // Write chunk1
    if (has2) {
        const int idx = lane + 64;
        float4 wv = ((const float4*)s_w)[idx];
        const float sc = (lane < 16) ? inv2 : inv3;
        float4 o;
        o.x = c.x * sc * wv.x;
        o.y = c.y * sc * wv.y;
        o.z = c.z * sc * wv.z;
        o.w = c.w * sc * wv.w;
        out4[idx] = o;
    }
}

extern "C" void kernel_launch(void* const* d_in, const int* in_sizes, int n_in,
                              void* d_out, int out_size, void* d_ws, size_t ws_size,
                              hipStream_t stream) {
    const float* node_input    = (const float*)d_in[0];
    const float* affine_weight = (const float*)d_in[1];
    const float* affine_bias   = (const float*)d_in[2];
    float* out = (float*)d_out;

    const int n_rows = in_sizes[0] / FEAT;   // 200000
    const int blocks = (n_rows + 3) / 4;     // 4 rows per block

    eln_kernel<<<blocks, 256, 0, stream>>>(node_input, affine_weight, affine_bias, out, n_rows);
}